// Round 12
// baseline (294.152 us; speedup 1.0000x reference)
//
#include <hip/hip_runtime.h>
#include <hip/hip_bf16.h>
#include <float.h>
#include <math.h>

// Problem dims (fixed by reference)
constexpr int B  = 4;
constexpr int D  = 512;
constexpr int C  = 2;
constexpr int Dc = 256;     // D / C
constexpr int FT = 256 * 256;   // 65536
constexpr int HW = 14 * 14;     // 196
constexpr int OUTC = 2 * Dc + D;  // 1024 output channels
constexpr float EPSV = 1e-8f;

typedef float f4 __attribute__((ext_vector_type(4)));

// Workspace layout (floats):
//   xp    @ 0      : B*D   = 2048
//   maps  @ 2048   : B*2*C*HW = 3136
//   mx    @ 5184   : B*2*C = 16
//   amax  @ 5200   : 16 (int)

// Kernel A: fused max-reduce over (F,T) + copy x -> out[:, 2*Dc + d].
// NT loads + NT stores (R2/R5/R8). R12 change: prefetch depth 2 (3 batches
// resident) — the pre-store vmcnt wait leaves batches i+1 AND i+2 in flight,
// doubling read-queue slack through each store burst vs R11's depth-1.
__global__ __launch_bounds__(256) void kA_maxcopy(const float* __restrict__ x,
                                                  float* __restrict__ out,
                                                  float* __restrict__ xp) {
    const int slice = blockIdx.x;            // b*D + d
    const int b = slice / D;
    const int d = slice % D;
    const f4* xs = (const f4*)(x + (size_t)slice * FT);
    f4* os = (f4*)(out + ((size_t)(b * OUTC + 2 * Dc + d)) * FT);
    const int tid = threadIdx.x;
    float m = -FLT_MAX;

    // 16384 f4 per slice; batch = 256 threads x 8 = 2048 f4; 8 batches.
    f4 c0[8], c1[8], c2[8];
    #pragma unroll
    for (int u = 0; u < 8; ++u)
        c0[u] = __builtin_nontemporal_load(&xs[tid + u * 256]);
    #pragma unroll
    for (int u = 0; u < 8; ++u)
        c1[u] = __builtin_nontemporal_load(&xs[tid + 2048 + u * 256]);

    #pragma unroll
    for (int it = 0; it < 8; ++it) {
        const int i0 = tid + it * 2048;
        if (it < 6) {
            #pragma unroll
            for (int u = 0; u < 8; ++u)
                c2[u] = __builtin_nontemporal_load(&xs[i0 + 4096 + u * 256]);
        }
        #pragma unroll
        for (int u = 0; u < 8; ++u) {
            __builtin_nontemporal_store(c0[u], &os[i0 + u * 256]);
            m = fmaxf(m, fmaxf(fmaxf(c0[u].x, c0[u].y), fmaxf(c0[u].z, c0[u].w)));
        }
        #pragma unroll
        for (int u = 0; u < 8; ++u) { c0[u] = c1[u]; c1[u] = c2[u]; }
    }

    // wave (64) reduce then cross-wave via LDS
    for (int off = 32; off; off >>= 1) m = fmaxf(m, __shfl_down(m, off, 64));
    __shared__ float sm[4];
    if ((tid & 63) == 0) sm[tid >> 6] = m;
    __syncthreads();
    if (tid == 0) {
        xp[slice] = fmaxf(fmaxf(sm[0], sm[1]), fmaxf(sm[2], sm[3]));
    }
}

// Kernel B: per (b,c) block — dots, norms, maps, per-(b,p,c) max/argmax
// (EXACT R7/R10 code — 8 blocks, proven)
__global__ __launch_bounds__(256) void kB_maps(const float* __restrict__ v0,
                                               const float* __restrict__ v1,
                                               const float* __restrict__ xp,
                                               float* __restrict__ maps,
                                               float* __restrict__ mx,
                                               int* __restrict__ amax) {
    const int bc = blockIdx.x;
    const int b = bc / C, c = bc % C;
    const int tid = threadIdx.x;          // blockDim.x == 256 == Dc

    __shared__ float sxc[Dc], sxo[Dc];
    sxc[tid] = xp[(b * C + c) * Dc + tid];         // xp[b, c, :]
    sxo[tid] = xp[(b * C + (1 - c)) * Dc + tid];   // xp[b, 1-c, :]
    __syncthreads();

    float ec = sxc[tid] * sxc[tid];
    float eo = sxo[tid] * sxo[tid];
    for (int off = 32; off; off >>= 1) {
        ec += __shfl_down(ec, off, 64);
        eo += __shfl_down(eo, off, 64);
    }
    __shared__ float red[8];
    const int lane = tid & 63, wid = tid >> 6;
    if (lane == 0) { red[wid] = ec; red[4 + wid] = eo; }
    __syncthreads();
    __shared__ float s_xn_c, s_xn_o;
    if (tid == 0) {
        s_xn_c = sqrtf(red[0] + red[1] + red[2] + red[3]);  // xn[b,0,c]
        s_xn_o = sqrtf(red[4] + red[5] + red[6] + red[7]);  // xn[b,1,c]
    }
    __syncthreads();
    const float xn_c = s_xn_c, xn_o = s_xn_o;

    float map0 = -FLT_MAX, map1 = -FLT_MAX;
    if (tid < HW) {
        const float* vv = (c == 0 ? v0 : v1) + (size_t)b * Dc * HW;
        float d0 = 0.f, d1 = 0.f, vs = 0.f;
        for (int dc = 0; dc < Dc; ++dc) {
            float v = vv[dc * HW + tid];
            d0 = fmaf(sxc[dc], v, d0);
            d1 = fmaf(sxo[dc], v, d1);
            vs = fmaf(v, v, vs);
        }
        float vn = sqrtf(vs);
        map0 = d0 / fmaxf(xn_c * vn, EPSV);
        map1 = d1 / fmaxf(xn_o * vn, EPSV);
        maps[((b * 2 + 0) * C + c) * HW + tid] = map0;
        maps[((b * 2 + 1) * C + c) * HW + tid] = map1;
    }

    __shared__ float rv[256];
    __shared__ int ri[256];
    for (int p = 0; p < 2; ++p) {
        __syncthreads();
        rv[tid] = (tid < HW) ? (p == 0 ? map0 : map1) : -FLT_MAX;
        ri[tid] = tid;
        __syncthreads();
        for (int s = 128; s; s >>= 1) {
            if (tid < s) {
                float v2 = rv[tid + s]; int i2 = ri[tid + s];
                if (v2 > rv[tid] || (v2 == rv[tid] && i2 < ri[tid])) {
                    rv[tid] = v2; ri[tid] = i2;
                }
            }
            __syncthreads();
        }
        if (tid == 0) {
            mx[(b * 2 + p) * C + c] = rv[0];
            amax[(b * 2 + p) * C + c] = ri[0];
        }
    }
}

// Kernel D': broadcast-fill out[:, 0:2*Dc]; selection derived redundantly
// per block from mx/amax; block 0 writes loss + att_maps. (EXACT R10 code.)
__global__ __launch_bounds__(256) void kD_fill_sel(const float* __restrict__ v0,
                                                   const float* __restrict__ v1,
                                                   const float* __restrict__ maps,
                                                   const float* __restrict__ mx,
                                                   const int* __restrict__ amax,
                                                   float* __restrict__ out) {
    const int n = blockIdx.x;               // b*(2*Dc) + c*Dc + dc
    const int b = n / (2 * Dc);
    const int r = n % (2 * Dc);
    const int c = r / Dc;
    const int dc = r % Dc;
    const int tid = threadIdx.x;

    const float s0 = mx[(b * 2 + 0) * C + 0] + mx[(b * 2 + 0) * C + 1];
    const float s1 = mx[(b * 2 + 1) * C + 0] + mx[(b * 2 + 1) * C + 1];
    const int p = (s1 > s0) ? 1 : 0;        // stable argsort(-scores): tie -> p=0
    const int hw = amax[(b * 2 + p) * C + c];

    const float* vv = (c == 0 ? v0 : v1);
    const float val = vv[((size_t)(b * Dc + dc)) * HW + hw];
    f4 v4 = {val, val, val, val};
    f4* os = (f4*)(out + ((size_t)(b * OUTC + c * Dc + dc)) * FT);
    for (int i0 = tid; i0 < FT / 4; i0 += 256 * 8) {
        #pragma unroll
        for (int u = 0; u < 8; ++u)
            __builtin_nontemporal_store(v4, &os[i0 + u * 256]);
    }

    if (n == 0) {
        if (tid == 0) {
            float L = 0.f;
            for (int bb = 0; bb < B; ++bb) {
                const float t0 = mx[(bb * 2 + 0) * C + 0] + mx[(bb * 2 + 0) * C + 1];
                const float t1 = mx[(bb * 2 + 1) * C + 0] + mx[(bb * 2 + 1) * C + 1];
                const int pb = (t1 > t0) ? 1 : 0;
                L += pb ? (t0 - t1) : (t1 - t0);
            }
            out[(size_t)B * OUTC * FT] = L / (float)B;
        }
        const size_t att_off = (size_t)B * OUTC * FT + 1;
        for (int i = tid; i < B * C * HW; i += 256) {
            const int bb = i / (C * HW);
            const int rr = i % (C * HW);
            const int cc = rr / HW, hh = rr % HW;
            const float t0 = mx[(bb * 2 + 0) * C + 0] + mx[(bb * 2 + 0) * C + 1];
            const float t1 = mx[(bb * 2 + 1) * C + 0] + mx[(bb * 2 + 1) * C + 1];
            const int pb = (t1 > t0) ? 1 : 0;
            out[att_off + i] = maps[((bb * 2 + pb) * C + cc) * HW + hh];
        }
    }
}

extern "C" void kernel_launch(void* const* d_in, const int* in_sizes, int n_in,
                              void* d_out, int out_size, void* d_ws, size_t ws_size,
                              hipStream_t stream) {
    const float* x  = (const float*)d_in[0];
    const float* v0 = (const float*)d_in[1];
    const float* v1 = (const float*)d_in[2];
    float* out = (float*)d_out;
    float* ws = (float*)d_ws;

    float* xp   = ws;                 // 2048
    float* maps = ws + 2048;          // 3136
    float* mx   = ws + 5184;          // 16
    int*   amax = (int*)(ws + 5200);  // 16

    kA_maxcopy<<<B * D, 256, 0, stream>>>(x, out, xp);
    kB_maps<<<B * C, 256, 0, stream>>>(v0, v1, xp, maps, mx, amax);
    kD_fill_sel<<<B * 2 * Dc, 256, 0, stream>>>(v0, v1, maps, mx, amax, out);
}